// Round 1
// baseline (43.113 us; speedup 1.0000x reference)
//
#include <hip/hip_runtime.h>
#include <math.h>

// Problem constants (match reference setup_inputs)
#define B 32
#define S 4096
#define E 256
#define H 256
#define T 64
#define J (T - 2)

// Kernel 1: d[b*S+s] = dot(encoder_output[b,s,:], We)
// One 64-lane wave per row; lane i handles float4 at element 4*i (E=256=64*4).
__global__ __launch_bounds__(256) void row_dot_kernel(
    const float* __restrict__ enc,
    const float* __restrict__ We,
    float* __restrict__ d) {
    const int gid  = blockIdx.x * blockDim.x + threadIdx.x;
    const int row  = gid >> 6;          // wave index == row index, grid sized exactly
    const int lane = threadIdx.x & 63;

    const float4* rowp = reinterpret_cast<const float4*>(enc + (size_t)row * E);
    const float4  v = rowp[lane];
    const float4  w = reinterpret_cast<const float4*>(We)[lane];
    float p = v.x * w.x + v.y * w.y + v.z * w.z + v.w * w.w;

#pragma unroll
    for (int off = 32; off >= 1; off >>= 1)
        p += __shfl_xor(p, off, 64);

    if (lane == 0) d[row] = p;
}

// Kernel 2: per batch b (one wave): segment means -> t[tau], then
// loss[b,j] = LSE_{m=j+2..63}(t[m]) - t[j+2]; write sum_j loss to loss_b[b].
__global__ __launch_bounds__(64) void seg_loss_kernel(
    const float* __restrict__ d,
    const int* __restrict__ ends,
    float* __restrict__ loss_b) {
    const int b   = blockIdx.x;
    const int tau = threadIdx.x;  // 0..63 == T

    __shared__ float tt[T];

    const int e  = ends[b * T + tau];
    const int st = (tau == 0) ? 0 : (ends[b * T + tau - 1] + 1);
    float s = 0.0f;
    for (int i = st; i <= e; ++i) s += d[b * S + i];
    tt[tau] = s / (float)(e - st + 1);
    __syncthreads();

    float lj = 0.0f;
    if (tau < J) {
        float M = -1e30f;
        for (int m = tau + 2; m < T; ++m) M = fmaxf(M, tt[m]);
        float acc = 0.0f;
        for (int m = tau + 2; m < T; ++m) acc += expf(tt[m] - M);
        lj = logf(acc) + M - tt[tau + 2];
    }

#pragma unroll
    for (int off = 32; off >= 1; off >>= 1)
        lj += __shfl_xor(lj, off, 64);

    if (tau == 0) loss_b[b] = lj;
}

// Kernel 3: final mean over B*J elements.
__global__ __launch_bounds__(64) void final_kernel(
    const float* __restrict__ loss_b,
    float* __restrict__ out) {
    const int lane = threadIdx.x;
    float v = (lane < B) ? loss_b[lane] : 0.0f;
#pragma unroll
    for (int off = 32; off >= 1; off >>= 1)
        v += __shfl_xor(v, off, 64);
    if (lane == 0) out[0] = v / (float)(B * J);
}

extern "C" void kernel_launch(void* const* d_in, const int* in_sizes, int n_in,
                              void* d_out, int out_size, void* d_ws, size_t ws_size,
                              hipStream_t stream) {
    // Input order per setup_inputs():
    // 0: encoder_output (B,S,E) f32
    // 1: his_turn_end_ids (B,T) i32
    // 2: W_ih, 3: W_hh, 4: b_ih, 5: b_hh  -- all dead (cancel in the loss)
    // 6: fc_w (1, H+E) f32 -> We = fc_w + H (Wh part is dead too)
    // 7: fc_b -- dead (cancels)
    const float* enc  = (const float*)d_in[0];
    const int*   ends = (const int*)d_in[1];
    const float* fc_w = (const float*)d_in[6];
    const float* We   = fc_w + H;

    float* d      = (float*)d_ws;      // B*S floats = 512 KiB
    float* loss_b = d + (size_t)B * S; // B floats
    float* out    = (float*)d_out;

    // Kernel 1: 4 waves/block, 1 row per wave -> grid = B*S/4 blocks.
    row_dot_kernel<<<(B * S) / 4, 256, 0, stream>>>(enc, We, d);
    // Kernel 2: one wave per batch.
    seg_loss_kernel<<<B, 64, 0, stream>>>(d, ends, loss_b);
    // Kernel 3: final reduction.
    final_kernel<<<1, 64, 0, stream>>>(loss_b, out);
}